// Round 13
// baseline (1868.242 us; speedup 1.0000x reference)
//
#include <hip/hip_runtime.h>
#include <stdint.h>

typedef unsigned short u16;
typedef short bf16x8 __attribute__((ext_vector_type(8)));
typedef float f32x4 __attribute__((ext_vector_type(4)));
typedef unsigned short u16x8 __attribute__((ext_vector_type(8)));

#define MFMA16(a, b, c) __builtin_amdgcn_mfma_f32_16x16x32_bf16((a), (b), (c), 0, 0, 0)

#define GLOAD_LDS16(gp, lp)                                                        \
  __builtin_amdgcn_global_load_lds((const __attribute__((address_space(1))) void*)(gp), \
                                   (__attribute__((address_space(3))) void*)(lp), 16, 0, 0)

#define BARRIER asm volatile("s_barrier" ::: "memory")
#define WAITV(n) asm volatile("s_waitcnt vmcnt(" #n ")" ::: "memory")
#define WAITL0 asm volatile("s_waitcnt lgkmcnt(0)" ::: "memory")

__device__ __forceinline__ u16 f2bf(float x) {
  union { float f; uint32_t u; } v; v.f = x;
  uint32_t r = (v.u + 0x7FFFu + ((v.u >> 16) & 1u)) >> 16;
  return (u16)r;
}

// ---------------- fused prep: qkvT transpose | oT transpose | LayerNorm ----------------
__device__ __forceinline__ void do_transpose(const float* __restrict__ in,
                                             u16* __restrict__ out, int R, int C,
                                             int bid, float (*tile)[65], int t) {
  int nCt = C >> 6;
  int r0 = (bid / nCt) << 6, c0 = (bid % nCt) << 6;
  int r = t >> 2, cg = (t & 3) << 4;
  const float* src = in + (size_t)(r0 + r) * C + c0 + cg;
#pragma unroll
  for (int i = 0; i < 4; i++) {
    float4 v = *reinterpret_cast<const float4*>(src + (i << 2));
    tile[r][cg + (i << 2) + 0] = v.x; tile[r][cg + (i << 2) + 1] = v.y;
    tile[r][cg + (i << 2) + 2] = v.z; tile[r][cg + (i << 2) + 3] = v.w;
  }
  __syncthreads();
  int c = t >> 2, rg = (t & 3) << 4;
  u16* dst = out + (size_t)(c0 + c) * R + r0 + rg;
#pragma unroll
  for (int i = 0; i < 2; i++) {
    u16x8 o8;
#pragma unroll
    for (int j2 = 0; j2 < 8; j2++) o8[j2] = f2bf(tile[rg + (i << 3) + j2][c]);
    *reinterpret_cast<u16x8*>(dst + (i << 3)) = o8;
  }
}

__device__ __forceinline__ void do_ln(const float* __restrict__ in,
                                      const float* __restrict__ w,
                                      const float* __restrict__ bia,
                                      u16* __restrict__ out, int row,
                                      float* red, int t) {
  const float* x = in + (size_t)row * 4096;
  float4 v[4];
  float s = 0.f, sq = 0.f;
#pragma unroll
  for (int i = 0; i < 4; i++) {
    v[i] = *reinterpret_cast<const float4*>(x + i * 1024 + t * 4);
    s  += v[i].x + v[i].y + v[i].z + v[i].w;
    sq += v[i].x * v[i].x + v[i].y * v[i].y + v[i].z * v[i].z + v[i].w * v[i].w;
  }
#pragma unroll
  for (int off = 32; off > 0; off >>= 1) { s += __shfl_down(s, off); sq += __shfl_down(sq, off); }
  int wid = t >> 6, lane = t & 63;
  if (lane == 0) { red[wid] = s; red[4 + wid] = sq; }
  __syncthreads();
  if (t == 0) {
    float st = red[0] + red[1] + red[2] + red[3];
    float sqt = red[4] + red[5] + red[6] + red[7];
    float mu = st * (1.f / 4096.f);
    float var = sqt * (1.f / 4096.f) - mu * mu;
    red[0] = mu; red[1] = rsqrtf(var + 1e-5f);
  }
  __syncthreads();
  float mu = red[0], rs = red[1];
#pragma unroll
  for (int i = 0; i < 4; i++) {
    float4 wv = *reinterpret_cast<const float4*>(w + i * 1024 + t * 4);
    float4 bv = *reinterpret_cast<const float4*>(bia + i * 1024 + t * 4);
    ushort4 u;
    u.x = f2bf((v[i].x - mu) * rs * wv.x + bv.x);
    u.y = f2bf((v[i].y - mu) * rs * wv.y + bv.y);
    u.z = f2bf((v[i].z - mu) * rs * wv.z + bv.z);
    u.w = f2bf((v[i].w - mu) * rs * wv.w + bv.w);
    *reinterpret_cast<ushort4*>(out + (size_t)row * 4096 + i * 1024 + t * 4) = u;
  }
}

__global__ __launch_bounds__(256) void prep_fused(const float* __restrict__ qkvw, u16* __restrict__ qkvT,
                                                  const float* __restrict__ ow, u16* __restrict__ oT,
                                                  const float* __restrict__ inp, const float* __restrict__ w,
                                                  const float* __restrict__ bia, u16* __restrict__ xn) {
  __shared__ float tile[64][65];
  int bid = blockIdx.x, t = threadIdx.x;
  if (bid < 12288)      do_transpose(qkvw, qkvT, 4096, 12288, bid, tile, t);
  else if (bid < 16384) do_transpose(ow, oT, 4096, 4096, bid - 12288, tile, t);
  else                  do_ln(inp, w, bia, xn, bid - 16384, &tile[0][0], t);
}

// ======================= 256x256 GEMM, r13: A-in-LDS / B-direct-from-L2 =======================
// C[M][N] = A[M][K] * Bt[N][K]^T, bf16 in, fp32 acc. 512 threads = 8 waves (2M x 4N).
// Binding constraint was LDS BW (256 KB/tile ≈ 3010 cyc > MFMA 620). B fragments have only
// 2-way cross-wave reuse and panels are L2/L3-resident (supertile raster) -> read B DIRECT
// from global into registers (VMEM pipe), double-buffered across tiles (bA/bB, 2-tile unroll).
// LDS holds only A: 2 x 32 KB dbuf, XOR-swizzled rows. LDS traffic 256->160 KB/tile.
// ONE barrier + ONE counted wait per tile (B is wave-private; only A-stage WAR remains).
// vmcnt ledger: per-tile issues = A0,A1 stages (4) then B(t+1) (8); WAITV(8) at tile end
// drains exactly the A stages; compiler-inserted waits cover B first-use (~1.5 tiles slack).
// NOTE (R11 errata): 32x32x16 MFMA with this swizzle = 7.5e7 bank conflicts. Keep 16x16x32.

#define LDA8(AR, Ab, mh) do {                                                     \
  _Pragma("unroll")                                                               \
  for (int mf = 0; mf < 4; mf++) {                                                \
    int lr = (mh)*128 + wm64 + mf*16 + llo;                                       \
    const char* rb = (Ab) + lr*128;                                               \
    int sw = (lr & 7) << 4;                                                       \
    AR[mf*2+0] = *reinterpret_cast<const bf16x8*>(rb + ((lhi16) ^ sw));           \
    AR[mf*2+1] = *reinterpret_cast<const bf16x8*>(rb + ((64 + lhi16) ^ sw));      \
  }                                                                               \
} while (0)

// B fragments direct from global: quadrant nh rows = n0 + wn*64 + nh*32 + nf*16 + llo,
// k-chunk = lhi*8 + c*32 (8 bf16 = 16B per load).
#define LDBD(BR0, BR1, ktile) do {                                                \
  const u16* gb_ = Bt + (size_t)(n0 + wn64 + llo) * K + (ktile)*64 + (lhi << 3);  \
  _Pragma("unroll")                                                               \
  for (int nf = 0; nf < 2; nf++) {                                                \
    BR0[nf*2+0] = *reinterpret_cast<const bf16x8*>(gb_ + (size_t)(nf*16) * K);       \
    BR0[nf*2+1] = *reinterpret_cast<const bf16x8*>(gb_ + (size_t)(nf*16) * K + 32);  \
    BR1[nf*2+0] = *reinterpret_cast<const bf16x8*>(gb_ + (size_t)(32 + nf*16) * K);      \
    BR1[nf*2+1] = *reinterpret_cast<const bf16x8*>(gb_ + (size_t)(32 + nf*16) * K + 32); \
  }                                                                               \
} while (0)

#define MMAQ(AR, BR, mh, nh) do {                                                 \
  _Pragma("unroll")                                                               \
  for (int mf = 0; mf < 4; mf++)                                                  \
    _Pragma("unroll")                                                             \
    for (int nf = 0; nf < 2; nf++) {                                              \
      acc[(mh)*4+mf][(nh)*2+nf] = MFMA16(AR[mf*2+0], BR[nf*2+0], acc[(mh)*4+mf][(nh)*2+nf]); \
      acc[(mh)*4+mf][(nh)*2+nf] = MFMA16(AR[mf*2+1], BR[nf*2+1], acc[(mh)*4+mf][(nh)*2+nf]); \
    }                                                                             \
} while (0)

#define STAGE_A(h, cbuf, ktile) do {                                              \
  char* lb_ = smc + (cbuf)*32768 + (h)*16384;                                     \
  _Pragma("unroll")                                                               \
  for (int i_ = 0; i_ < 2; i_++) {                                                \
    int L_ = i_*512 + t;                                                          \
    int lr_ = (h)*128 + (L_ >> 3);                                                \
    int sl_ = (L_ & 7) ^ (lr_ & 7);                                               \
    int r_ = (lr_ & 63) | ((lr_ & 64) << 1) | ((lr_ & 128) >> 1);                 \
    GLOAD_LDS16(A + (size_t)(m0 + r_) * K + (ktile)*64 + sl_*8, lb_ + L_*16);     \
  }                                                                               \
} while (0)

// One K-tile, one barrier. S: stage A(t+1) + load B(t+1) into BN regs.
#define TILE1(tt, S, BC0, BC1, BN0, BN1) do {                                     \
  int c_ = (tt) & 1;                                                              \
  const char* Ab = smc + c_ * 32768;                                              \
  LDA8(aR, Ab, 0);                                                                \
  if (S) { STAGE_A(0, c_ ^ 1, (tt) + 1); STAGE_A(1, c_ ^ 1, (tt) + 1); }          \
  __builtin_amdgcn_s_setprio(1);                                                  \
  MMAQ(aR, BC0, 0, 0); MMAQ(aR, BC1, 0, 1);                                       \
  __builtin_amdgcn_s_setprio(0);                                                  \
  if (S) LDBD(BN0, BN1, (tt) + 1);                                                \
  LDA8(aR, Ab, 1);                                                                \
  __builtin_amdgcn_s_setprio(1);                                                  \
  MMAQ(aR, BC1, 1, 1); MMAQ(aR, BC0, 1, 0);                                       \
  __builtin_amdgcn_s_setprio(0);                                                  \
  if (S) { WAITV(8); } else { WAITV(0); }                                         \
  WAITL0; BARRIER;                                                                \
} while (0)

template <int EPI>
__global__ __launch_bounds__(512, 2) void gemm256(const u16* __restrict__ A, const u16* __restrict__ Bt,
                                                  void* __restrict__ Cout, u16* __restrict__ vT,
                                                  int M, int N, int K, int nbn) {
  __shared__ u16 sm[32768];  // 64 KiB: 2 x 32 KiB A-tile dbuf
  char* smc = (char*)sm;
  int bid = blockIdx.x;
  // --- supertile raster (16x16 tiles per 256 blocks; XCD 4x8 sub-rect) ---
  int s = bid >> 8, local = bid & 255;
  int xcd = local & 7, j = local >> 3;
  int trow = ((xcd >> 1) << 2) + (j >> 3);   // 0..15
  int tcol = ((xcd & 1) << 3) + (j & 7);     // 0..15
  int nsc = nbn >> 4;
  int sr = s / nsc, sc = s - sr * nsc;
  int tm = (sr << 4) + trow, tn = (sc << 4) + tcol;
  int m0 = tm << 8, n0 = tn << 8;
  int t = threadIdx.x;
  int w = t >> 6, lane = t & 63;
  int wm = w >> 2, wn = w & 3;
  int llo = lane & 15, lhi = lane >> 4;
  int wm64 = wm << 6, wn64 = wn << 6, lhi16 = lhi << 4;
  f32x4 acc[8][4] = {};
  bf16x8 aR[8], bA0[4], bA1[4], bB0[4], bB1[4];
  int NT = K >> 6;  // 64 for both GEMMs (even)
  // prologue: stage A(0) [4 gloads], load B(0) [8 loads]; drain A stages only.
  STAGE_A(0, 0, 0); STAGE_A(1, 0, 0);
  LDBD(bA0, bA1, 0);
  WAITV(8); BARRIER;
#pragma unroll 1
  for (int tt = 0; tt < NT - 2; tt += 2) {
    TILE1(tt, 1, bA0, bA1, bB0, bB1);
    TILE1(tt + 1, 1, bB0, bB1, bA0, bA1);
  }
  TILE1(NT - 2, 1, bA0, bA1, bB0, bB1);
  TILE1(NT - 1, 0, bB0, bB1, bA0, bA1);
  // ---- epilogue ----
  if (EPI == 2) {
    float* C = (float*)Cout;
#pragma unroll
    for (int mi = 0; mi < 8; mi++)
#pragma unroll
      for (int ni = 0; ni < 4; ni++) {
        int m = m0 + wm * 128 + mi * 16 + lhi * 4;
        int n = n0 + wn * 64 + ni * 16 + llo;
#pragma unroll
        for (int r = 0; r < 4; r++) C[(size_t)(m + r) * N + n] = acc[mi][ni][r];
      }
  } else {
    if (n0 < 8192) {
      u16* qkb = (u16*)Cout;
#pragma unroll
      for (int mi = 0; mi < 8; mi++)
#pragma unroll
        for (int ni = 0; ni < 4; ni++) {
          int m = m0 + wm * 128 + mi * 16 + lhi * 4;
          int n = n0 + wn * 64 + ni * 16 + llo;
#pragma unroll
          for (int r = 0; r < 4; r++) qkb[(size_t)(m + r) * 8192 + n] = f2bf(acc[mi][ni][r]);
        }
    } else {
#pragma unroll
      for (int mi = 0; mi < 8; mi++)
#pragma unroll
        for (int ni = 0; ni < 4; ni++) {
          int m = m0 + wm * 128 + mi * 16 + lhi * 4;
          int n_ = n0 + wn * 64 + ni * 16 + llo - 8192;
          int h = n_ >> 8, d = n_ & 255;
          int b = m >> 8, s2 = m & 255;
          ushort4 u;
          u.x = f2bf(acc[mi][ni][0]); u.y = f2bf(acc[mi][ni][1]);
          u.z = f2bf(acc[mi][ni][2]); u.w = f2bf(acc[mi][ni][3]);
          *reinterpret_cast<ushort4*>(vT + ((size_t)((b << 4) + h) * 256 + d) * 256 + s2) = u;
        }
    }
  }
}

// ---------------- attention (r10 champion): 512 threads / 8 waves, 128 q-rows per block,
// block = (b, h, half). K/V double-buffered 2x32 KiB, raw s_barrier + counted vmcnt;
// stage(t+1) under compute(t); P wave-private (lgkmcnt(0) only).
__global__ __launch_bounds__(512) void attn_kernel(const u16* __restrict__ qk,
                                                   const u16* __restrict__ vT,
                                                   const int* __restrict__ mask,
                                                   u16* __restrict__ ctx) {
  __shared__ u16 KV[2 * 32 * 1024 / 2];  // 64 KiB: 2 x 32 KiB K/V tile buffers
  __shared__ u16 P[128 * 256];           // 64 KiB: probs [128 q][256 key]
  __shared__ float maskf[256];
  char* kv0 = (char*)KV;
  int bid = blockIdx.x;
  int half = bid & 1, h = (bid >> 1) & 15, b = bid >> 5;
  int bh = (b << 4) + h;
  int t = threadIdx.x, wid = t >> 6, lane = t & 63, llo = lane & 15, lhi = lane >> 4;
  if (t < 256) maskf[t] = mask[(b << 8) + t] ? -1e30f : 0.0f;
  bf16x8 qf[8];
  {
    const u16* qrow = qk + (size_t)((b << 8) + (half << 7) + (wid << 4) + llo) * 8192 + (h << 8);
#pragma unroll
    for (int c = 0; c < 8; c++)
      qf[c] = *reinterpret_cast<const bf16x8*>(qrow + (lhi << 3) + (c << 5));
  }
#define STAGE_K(kt, buf) do {                                                      \
    char* lb_ = kv0 + (buf) * 32768;                                               \
    _Pragma("unroll")                                                              \
    for (int i_ = 0; i_ < 4; i_++) {                                               \
      int G_ = (i_ << 9) + t;                                                      \
      int key_ = G_ >> 5, g_ = G_ & 31;                                            \
      int gs_ = g_ ^ (key_ & 7);                                                   \
      const u16* src_ = qk + (size_t)((b << 8) + ((kt) << 6) + key_) * 8192 + 4096 \
                        + (h << 8) + (gs_ << 3);                                   \
      GLOAD_LDS16(src_, lb_ + (G_ << 4));                                          \
    }                                                                              \
  } while (0)
#define STAGE_V(j, buf) do {                                                       \
    char* lb_ = kv0 + (buf) * 32768;                                               \
    _Pragma("unroll")                                                              \
    for (int i_ = 0; i_ < 4; i_++) {                                               \
      int G_ = (i_ << 9) + t;                                                      \
      int d_ = G_ >> 3, g_ = G_ & 7;                                               \
      int gs_ = g_ ^ (d_ & 7);                                                     \
      const u16* src_ = vT + ((size_t)bh * 256 + d_) * 256 + ((j) << 6) + (gs_ << 3); \
      GLOAD_LDS16(src_, lb_ + (G_ << 4));                                          \
    }                                                                              \
  } while (0)
  f32x4 sacc[16] = {};
  STAGE_K(0, 0);
#pragma unroll 1
  for (int kt = 0; kt < 4; kt++) {
    if (kt < 3) STAGE_K(kt + 1, (kt + 1) & 1); else STAGE_V(0, 0);
    WAITV(4); BARRIER;
    const char* kb0 = kv0 + (kt & 1) * 32768;
#pragma unroll
    for (int nf = 0; nf < 4; nf++) {
      int kl = (nf << 4) + llo;
      const char* kb = kb0 + (kl << 9);
      int sw = (kl & 7) << 4;
#pragma unroll
      for (int c = 0; c < 8; c++) {
        bf16x8 kf = *reinterpret_cast<const bf16x8*>(kb + (((lhi << 4) + (c << 6)) ^ sw));
        sacc[kt * 4 + nf] = MFMA16(qf[c], kf, sacc[kt * 4 + nf]);
      }
    }
    WAITL0; BARRIER;
  }
  float madd[16];
#pragma unroll
  for (int f = 0; f < 16; f++) madd[f] = maskf[(f << 4) + llo];
  float mx[4] = {-3e38f, -3e38f, -3e38f, -3e38f};
#pragma unroll
  for (int f = 0; f < 16; f++)
#pragma unroll
    for (int r = 0; r < 4; r++) {
      float sv = sacc[f][r] * 0.0625f + madd[f];
      sacc[f][r] = sv;
      mx[r] = fmaxf(mx[r], sv);
    }
#pragma unroll
  for (int r = 0; r < 4; r++)
#pragma unroll
    for (int d = 1; d < 16; d <<= 1) mx[r] = fmaxf(mx[r], __shfl_xor(mx[r], d));
  float sum[4] = {0.f, 0.f, 0.f, 0.f};
#pragma unroll
  for (int f = 0; f < 16; f++)
#pragma unroll
    for (int r = 0; r < 4; r++) {
      float p = __expf(sacc[f][r] - mx[r]);
      sacc[f][r] = p;
      sum[r] += p;
    }
#pragma unroll
  for (int r = 0; r < 4; r++)
#pragma unroll
    for (int d = 1; d < 16; d <<= 1) sum[r] += __shfl_xor(sum[r], d);
  float rin[4];
#pragma unroll
  for (int r = 0; r < 4; r++) rin[r] = 1.f / sum[r];
#pragma unroll
  for (int r = 0; r < 4; r++) {
    int q = (wid << 4) + (lhi << 2) + r;
    char* pb = (char*)P + (q << 9);
    int sw = (q & 7) << 4;
#pragma unroll
    for (int f = 0; f < 16; f++) {
      int key = (f << 4) + llo;
      *reinterpret_cast<u16*>(pb + ((key << 1) ^ sw)) = f2bf(sacc[f][r] * rin[r]);
    }
  }
  WAITL0;
  f32x4 cacc[16] = {};
#pragma unroll 1
  for (int j = 0; j < 4; j++) {
    if (j < 3) { STAGE_V(j + 1, (j + 1) & 1); WAITV(4); } else { WAITV(0); }
    BARRIER;
    const char* vb0 = kv0 + (j & 1) * 32768;
    bf16x8 pf[2];
    {
      int q = (wid << 4) + llo;
      const char* pb = (const char*)P + (q << 9);
      int sw = (q & 7) << 4;
#pragma unroll
      for (int c = 0; c < 2; c++)
        pf[c] = *reinterpret_cast<const bf16x8*>(pb + (((j << 7) + (c << 6) + (lhi << 4)) ^ sw));
    }
#pragma unroll
    for (int mf = 0; mf < 16; mf++) {
      int dl = (mf << 4) + llo;
      const char* vb = vb0 + (dl << 7);
      int sw = (dl & 7) << 4;
#pragma unroll
      for (int c = 0; c < 2; c++) {
        bf16x8 vf = *reinterpret_cast<const bf16x8*>(vb + (((lhi << 4) + (c << 6)) ^ sw));
        cacc[mf] = MFMA16(vf, pf[c], cacc[mf]);
      }
    }
    if (j < 3) { WAITL0; BARRIER; }
  }
#undef STAGE_K
#undef STAGE_V
  int token = (b << 8) + (half << 7) + (wid << 4) + llo;
  u16* crow = ctx + (size_t)token * 4096 + (h << 8);
#pragma unroll
  for (int mf = 0; mf < 16; mf++) {
    ushort4 u;
    u.x = f2bf(cacc[mf][0]); u.y = f2bf(cacc[mf][1]);
    u.z = f2bf(cacc[mf][2]); u.w = f2bf(cacc[mf][3]);
    *reinterpret_cast<ushort4*>(crow + (mf << 4) + (lhi << 2)) = u;
  }
}

extern "C" void kernel_launch(void* const* d_in, const int* in_sizes, int n_in,
                              void* d_out, int out_size, void* d_ws, size_t ws_size,
                              hipStream_t stream) {
  const float* inp  = (const float*)d_in[0];
  const int*   mask = (const int*)d_in[1];
  const float* w    = (const float*)d_in[2];
  const float* bia  = (const float*)d_in[3];
  const float* qkvw = (const float*)d_in[4];
  const float* ow   = (const float*)d_in[5];
  const size_t MB = 1024ull * 1024ull;
  if (ws_size < 384 * MB) return;  // layout below needs 384 MiB
  char* ws = (char*)d_ws;
  u16* xn   = (u16*)(ws);             // 64 MiB  [0,64)
  u16* qkvT = (u16*)(ws + 64 * MB);   // 96 MiB  [64,160)
  u16* qk   = (u16*)(ws + 160 * MB);  // 128 MiB [160,288): [8192 tok][8192]
  u16* vT   = (u16*)(ws + 288 * MB);  // 64 MiB  [288,352): [b][h][d][s]
  u16* oT2  = (u16*)(ws + 352 * MB);  // 32 MiB  [352,384)
  u16* ctx  = (u16*)(ws);             // overlays xn (dead after QKV GEMM)
  float* out = (float*)d_out;

  prep_fused<<<24576, 256, 0, stream>>>(qkvw, qkvT, ow, oT2, inp, w, bia, xn);
  gemm256<1><<<1536, 512, 0, stream>>>(xn, qkvT, (void*)qk, vT, 8192, 12288, 4096, 48);
  attn_kernel<<<1024, 512, 0, stream>>>(qk, vT, mask, ctx);
  gemm256<2><<<512, 512, 0, stream>>>(ctx, oT2, (void*)out, nullptr, 8192, 4096, 4096, 16);
}

// Round 14
// 1229.390 us; speedup vs baseline: 1.5196x; 1.5196x over previous
//
#include <hip/hip_runtime.h>
#include <stdint.h>

typedef unsigned short u16;
typedef short bf16x8 __attribute__((ext_vector_type(8)));
typedef float f32x4 __attribute__((ext_vector_type(4)));
typedef unsigned short u16x8 __attribute__((ext_vector_type(8)));

#define MFMA16(a, b, c) __builtin_amdgcn_mfma_f32_16x16x32_bf16((a), (b), (c), 0, 0, 0)

#define GLOAD_LDS16(gp, lp)                                                        \
  __builtin_amdgcn_global_load_lds((const __attribute__((address_space(1))) void*)(gp), \
                                   (__attribute__((address_space(3))) void*)(lp), 16, 0, 0)

#define BARRIER asm volatile("s_barrier" ::: "memory")
#define WAITV(n) asm volatile("s_waitcnt vmcnt(" #n ")" ::: "memory")
#define WAITL0 asm volatile("s_waitcnt lgkmcnt(0)" ::: "memory")

__device__ __forceinline__ u16 f2bf(float x) {
  union { float f; uint32_t u; } v; v.f = x;
  uint32_t r = (v.u + 0x7FFFu + ((v.u >> 16) & 1u)) >> 16;
  return (u16)r;
}

// ---------------- fused prep: qkvT transpose | oT transpose | LayerNorm ----------------
__device__ __forceinline__ void do_transpose(const float* __restrict__ in,
                                             u16* __restrict__ out, int R, int C,
                                             int bid, float (*tile)[65], int t) {
  int nCt = C >> 6;
  int r0 = (bid / nCt) << 6, c0 = (bid % nCt) << 6;
  int r = t >> 2, cg = (t & 3) << 4;
  const float* src = in + (size_t)(r0 + r) * C + c0 + cg;
#pragma unroll
  for (int i = 0; i < 4; i++) {
    float4 v = *reinterpret_cast<const float4*>(src + (i << 2));
    tile[r][cg + (i << 2) + 0] = v.x; tile[r][cg + (i << 2) + 1] = v.y;
    tile[r][cg + (i << 2) + 2] = v.z; tile[r][cg + (i << 2) + 3] = v.w;
  }
  __syncthreads();
  int c = t >> 2, rg = (t & 3) << 4;
  u16* dst = out + (size_t)(c0 + c) * R + r0 + rg;
#pragma unroll
  for (int i = 0; i < 2; i++) {
    u16x8 o8;
#pragma unroll
    for (int j2 = 0; j2 < 8; j2++) o8[j2] = f2bf(tile[rg + (i << 3) + j2][c]);
    *reinterpret_cast<u16x8*>(dst + (i << 3)) = o8;
  }
}

__device__ __forceinline__ void do_ln(const float* __restrict__ in,
                                      const float* __restrict__ w,
                                      const float* __restrict__ bia,
                                      u16* __restrict__ out, int row,
                                      float* red, int t) {
  const float* x = in + (size_t)row * 4096;
  float4 v[4];
  float s = 0.f, sq = 0.f;
#pragma unroll
  for (int i = 0; i < 4; i++) {
    v[i] = *reinterpret_cast<const float4*>(x + i * 1024 + t * 4);
    s  += v[i].x + v[i].y + v[i].z + v[i].w;
    sq += v[i].x * v[i].x + v[i].y * v[i].y + v[i].z * v[i].z + v[i].w * v[i].w;
  }
#pragma unroll
  for (int off = 32; off > 0; off >>= 1) { s += __shfl_down(s, off); sq += __shfl_down(sq, off); }
  int wid = t >> 6, lane = t & 63;
  if (lane == 0) { red[wid] = s; red[4 + wid] = sq; }
  __syncthreads();
  if (t == 0) {
    float st = red[0] + red[1] + red[2] + red[3];
    float sqt = red[4] + red[5] + red[6] + red[7];
    float mu = st * (1.f / 4096.f);
    float var = sqt * (1.f / 4096.f) - mu * mu;
    red[0] = mu; red[1] = rsqrtf(var + 1e-5f);
  }
  __syncthreads();
  float mu = red[0], rs = red[1];
#pragma unroll
  for (int i = 0; i < 4; i++) {
    float4 wv = *reinterpret_cast<const float4*>(w + i * 1024 + t * 4);
    float4 bv = *reinterpret_cast<const float4*>(bia + i * 1024 + t * 4);
    ushort4 u;
    u.x = f2bf((v[i].x - mu) * rs * wv.x + bv.x);
    u.y = f2bf((v[i].y - mu) * rs * wv.y + bv.y);
    u.z = f2bf((v[i].z - mu) * rs * wv.z + bv.z);
    u.w = f2bf((v[i].w - mu) * rs * wv.w + bv.w);
    *reinterpret_cast<ushort4*>(out + (size_t)row * 4096 + i * 1024 + t * 4) = u;
  }
}

__global__ __launch_bounds__(256) void prep_fused(const float* __restrict__ qkvw, u16* __restrict__ qkvT,
                                                  const float* __restrict__ ow, u16* __restrict__ oT,
                                                  const float* __restrict__ inp, const float* __restrict__ w,
                                                  const float* __restrict__ bia, u16* __restrict__ xn) {
  __shared__ float tile[64][65];
  int bid = blockIdx.x, t = threadIdx.x;
  if (bid < 12288)      do_transpose(qkvw, qkvT, 4096, 12288, bid, tile, t);
  else if (bid < 16384) do_transpose(ow, oT, 4096, 4096, bid - 12288, tile, t);
  else                  do_ln(inp, w, bia, xn, bid - 16384, &tile[0][0], t);
}

// ======================= 256x256 pipe-overlap GEMM (R6/R12 champion) =======================
// C[M][N] = A[M][K] * Bt[N][K]^T, bf16 in, fp32 acc. 512 threads = 8 waves (2M x 4N).
// LDS 128 KiB: 2 buffers x (A[256][64] + B[256][64]) bf16, XOR-swizzled rows.
// Supertile raster (L3) + XCD 4x8 sub-rect (L2). No barrier between a group's
// ds_reads and its MFMAs (counted lgkmcnt overlap + wave skew); 2 barriers/K-tile
// (provably minimal for cross-wave dbuf staging), each preceded by lgkmcnt(0).
// vmcnt ledger: steady invariant [A0(t+1),B1(t+1)].
// ERRATA LOG: R11 32x32x16 w/ this swizzle = 7.5e7 bank conflicts (-13%). R13
// B-direct-from-L2 = latency-bound (-75%). Fragment reads belong in LDS; keep 16x16x32.

#define LDA8(AR, Ab, mh) do {                                                     \
  _Pragma("unroll")                                                               \
  for (int mf = 0; mf < 4; mf++) {                                                \
    int lr = (mh)*128 + wm64 + mf*16 + llo;                                       \
    const char* rb = (Ab) + lr*128;                                               \
    int sw = (lr & 7) << 4;                                                       \
    AR[mf*2+0] = *reinterpret_cast<const bf16x8*>(rb + ((lhi16) ^ sw));           \
    AR[mf*2+1] = *reinterpret_cast<const bf16x8*>(rb + ((64 + lhi16) ^ sw));      \
  }                                                                               \
} while (0)

#define LDB4(BR, Bb, nh) do {                                                     \
  _Pragma("unroll")                                                               \
  for (int nf = 0; nf < 2; nf++) {                                                \
    int lr = (nh)*128 + wn32 + nf*16 + llo;                                       \
    const char* rb = (Bb) + lr*128;                                               \
    int sw = (lr & 7) << 4;                                                       \
    BR[nf*2+0] = *reinterpret_cast<const bf16x8*>(rb + ((lhi16) ^ sw));           \
    BR[nf*2+1] = *reinterpret_cast<const bf16x8*>(rb + ((64 + lhi16) ^ sw));      \
  }                                                                               \
} while (0)

#define MMAQ(AR, BR, mh, nh) do {                                                 \
  _Pragma("unroll")                                                               \
  for (int mf = 0; mf < 4; mf++)                                                  \
    _Pragma("unroll")                                                             \
    for (int nf = 0; nf < 2; nf++) {                                              \
      acc[(mh)*4+mf][(nh)*2+nf] = MFMA16(AR[mf*2+0], BR[nf*2+0], acc[(mh)*4+mf][(nh)*2+nf]); \
      acc[(mh)*4+mf][(nh)*2+nf] = MFMA16(AR[mf*2+1], BR[nf*2+1], acc[(mh)*4+mf][(nh)*2+nf]); \
    }                                                                             \
} while (0)

#define STAGE(isB, h, cbuf, ktile) do {                                           \
  const u16* g_ = (isB) ? Bt : A;                                                 \
  int base0_ = (isB) ? n0 : m0;                                                   \
  char* lb_ = smc + (cbuf)*65536 + (isB)*32768 + (h)*16384;                       \
  _Pragma("unroll")                                                               \
  for (int i_ = 0; i_ < 2; i_++) {                                                \
    int L_ = i_*512 + t;                                                          \
    int lr_ = (h)*128 + (L_ >> 3);                                                \
    int sl_ = (L_ & 7) ^ (lr_ & 7);                                               \
    int r_ = (isB) ? (((lr_ & 128) >> 2) | ((lr_ & 96) << 1) | (lr_ & 31))        \
                   : ((lr_ & 63) | ((lr_ & 64) << 1) | ((lr_ & 128) >> 1));       \
    GLOAD_LDS16(g_ + (size_t)(base0_ + r_) * K + (ktile)*64 + sl_*8, lb_ + L_*16);\
  }                                                                               \
} while (0)

#define TILE2(tt, S1, S2, W2) do {                                                \
  int c_ = (tt) & 1;                                                              \
  const char* Ab = smc + c_ * 65536;                                              \
  const char* Bb = Ab + 32768;                                                    \
  /* G1: reads a0,b0,b1 | stage t+1 | MFMA Q00,Q01 (no barrier between) */        \
  LDA8(aR, Ab, 0); LDB4(b0R, Bb, 0); LDB4(b1R, Bb, 1);                            \
  if (S1) { STAGE(1, 0, c_ ^ 1, (tt) + 1); STAGE(0, 1, c_ ^ 1, (tt) + 1); }       \
  __builtin_amdgcn_s_setprio(1);                                                  \
  MMAQ(aR, b0R, 0, 0); MMAQ(aR, b1R, 0, 1);                                       \
  __builtin_amdgcn_s_setprio(0);                                                  \
  WAITL0; BARRIER;                                                                \
  /* G2: reads a1 | stage t+2 | MFMA Q11,Q10 */                                   \
  LDA8(aR, Ab, 1);                                                                \
  if (S2) { STAGE(0, 0, c_, (tt) + 2); STAGE(1, 1, c_, (tt) + 2); }               \
  __builtin_amdgcn_s_setprio(1);                                                  \
  MMAQ(aR, b1R, 1, 1); MMAQ(aR, b0R, 1, 0);                                       \
  __builtin_amdgcn_s_setprio(0);                                                  \
  WAITV(W2); WAITL0; BARRIER;                                                     \
} while (0)

template <int EPI>
__global__ __launch_bounds__(512, 2) void gemm256(const u16* __restrict__ A, const u16* __restrict__ Bt,
                                                  void* __restrict__ Cout, u16* __restrict__ vT,
                                                  int M, int N, int K, int nbn) {
  __shared__ u16 sm[65536];  // 128 KiB
  char* smc = (char*)sm;
  int bid = blockIdx.x;
  // --- supertile raster (16x16 tiles per 256 blocks; XCD 4x8 sub-rect) ---
  int s = bid >> 8, local = bid & 255;
  int xcd = local & 7, j = local >> 3;
  int trow = ((xcd >> 1) << 2) + (j >> 3);   // 0..15
  int tcol = ((xcd & 1) << 3) + (j & 7);     // 0..15
  int nsc = nbn >> 4;
  int sr = s / nsc, sc = s - sr * nsc;
  int tm = (sr << 4) + trow, tn = (sc << 4) + tcol;
  int m0 = tm << 8, n0 = tn << 8;
  int t = threadIdx.x;
  int w = t >> 6, lane = t & 63;
  int wm = w >> 2, wn = w & 3;
  int llo = lane & 15, lhi = lane >> 4;
  int wm64 = wm << 6, wn32 = wn << 5, lhi16 = lhi << 4;
  f32x4 acc[8][4] = {};
  bf16x8 aR[8], b0R[4], b1R[4];
  int NT = K >> 6;
  // prologue queue: A0(0),B0(0),B1(0),A1(0),A0(1),B1(1) = 12 loads; vmcnt(4)
  STAGE(0, 0, 0, 0); STAGE(1, 0, 0, 0); STAGE(1, 1, 0, 0); STAGE(0, 1, 0, 0);
  STAGE(0, 0, 1, 1); STAGE(1, 1, 1, 1);
  WAITV(4); BARRIER;
#pragma unroll 1
  for (int tt = 0; tt < NT - 2; ++tt) TILE2(tt, 1, 1, 4);
  TILE2(NT - 2, 1, 0, 0);
  TILE2(NT - 1, 0, 0, 0);
  // ---- epilogue ----
  if (EPI == 2) {
    float* C = (float*)Cout;
#pragma unroll
    for (int mi = 0; mi < 8; mi++)
#pragma unroll
      for (int ni = 0; ni < 4; ni++) {
        int m = m0 + wm * 128 + mi * 16 + lhi * 4;
        int n = n0 + wn * 64 + ni * 16 + llo;
#pragma unroll
        for (int r = 0; r < 4; r++) C[(size_t)(m + r) * N + n] = acc[mi][ni][r];
      }
  } else {
    if (n0 < 8192) {
      u16* qkb = (u16*)Cout;
#pragma unroll
      for (int mi = 0; mi < 8; mi++)
#pragma unroll
        for (int ni = 0; ni < 4; ni++) {
          int m = m0 + wm * 128 + mi * 16 + lhi * 4;
          int n = n0 + wn * 64 + ni * 16 + llo;
#pragma unroll
          for (int r = 0; r < 4; r++) qkb[(size_t)(m + r) * 8192 + n] = f2bf(acc[mi][ni][r]);
        }
    } else {
#pragma unroll
      for (int mi = 0; mi < 8; mi++)
#pragma unroll
        for (int ni = 0; ni < 4; ni++) {
          int m = m0 + wm * 128 + mi * 16 + lhi * 4;
          int n_ = n0 + wn * 64 + ni * 16 + llo - 8192;
          int h = n_ >> 8, d = n_ & 255;
          int b = m >> 8, s2 = m & 255;
          ushort4 u;
          u.x = f2bf(acc[mi][ni][0]); u.y = f2bf(acc[mi][ni][1]);
          u.z = f2bf(acc[mi][ni][2]); u.w = f2bf(acc[mi][ni][3]);
          *reinterpret_cast<ushort4*>(vT + ((size_t)((b << 4) + h) * 256 + d) * 256 + s2) = u;
        }
    }
  }
}

// ---------------- attention (r10 champion): 512 threads / 8 waves, 128 q-rows per block,
// block = (b, h, half). K/V double-buffered 2x32 KiB, raw s_barrier + counted vmcnt;
// stage(t+1) under compute(t); P wave-private (lgkmcnt(0) only).
__global__ __launch_bounds__(512) void attn_kernel(const u16* __restrict__ qk,
                                                   const u16* __restrict__ vT,
                                                   const int* __restrict__ mask,
                                                   u16* __restrict__ ctx) {
  __shared__ u16 KV[2 * 32 * 1024 / 2];  // 64 KiB: 2 x 32 KiB K/V tile buffers
  __shared__ u16 P[128 * 256];           // 64 KiB: probs [128 q][256 key]
  __shared__ float maskf[256];
  char* kv0 = (char*)KV;
  int bid = blockIdx.x;
  int half = bid & 1, h = (bid >> 1) & 15, b = bid >> 5;
  int bh = (b << 4) + h;
  int t = threadIdx.x, wid = t >> 6, lane = t & 63, llo = lane & 15, lhi = lane >> 4;
  if (t < 256) maskf[t] = mask[(b << 8) + t] ? -1e30f : 0.0f;
  bf16x8 qf[8];
  {
    const u16* qrow = qk + (size_t)((b << 8) + (half << 7) + (wid << 4) + llo) * 8192 + (h << 8);
#pragma unroll
    for (int c = 0; c < 8; c++)
      qf[c] = *reinterpret_cast<const bf16x8*>(qrow + (lhi << 3) + (c << 5));
  }
#define STAGE_K(kt, buf) do {                                                      \
    char* lb_ = kv0 + (buf) * 32768;                                               \
    _Pragma("unroll")                                                              \
    for (int i_ = 0; i_ < 4; i_++) {                                               \
      int G_ = (i_ << 9) + t;                                                      \
      int key_ = G_ >> 5, g_ = G_ & 31;                                            \
      int gs_ = g_ ^ (key_ & 7);                                                   \
      const u16* src_ = qk + (size_t)((b << 8) + ((kt) << 6) + key_) * 8192 + 4096 \
                        + (h << 8) + (gs_ << 3);                                   \
      GLOAD_LDS16(src_, lb_ + (G_ << 4));                                          \
    }                                                                              \
  } while (0)
#define STAGE_V(j, buf) do {                                                       \
    char* lb_ = kv0 + (buf) * 32768;                                               \
    _Pragma("unroll")                                                              \
    for (int i_ = 0; i_ < 4; i_++) {                                               \
      int G_ = (i_ << 9) + t;                                                      \
      int d_ = G_ >> 3, g_ = G_ & 7;                                               \
      int gs_ = g_ ^ (d_ & 7);                                                     \
      const u16* src_ = vT + ((size_t)bh * 256 + d_) * 256 + ((j) << 6) + (gs_ << 3); \
      GLOAD_LDS16(src_, lb_ + (G_ << 4));                                          \
    }                                                                              \
  } while (0)
  f32x4 sacc[16] = {};
  STAGE_K(0, 0);
#pragma unroll 1
  for (int kt = 0; kt < 4; kt++) {
    if (kt < 3) STAGE_K(kt + 1, (kt + 1) & 1); else STAGE_V(0, 0);
    WAITV(4); BARRIER;
    const char* kb0 = kv0 + (kt & 1) * 32768;
#pragma unroll
    for (int nf = 0; nf < 4; nf++) {
      int kl = (nf << 4) + llo;
      const char* kb = kb0 + (kl << 9);
      int sw = (kl & 7) << 4;
#pragma unroll
      for (int c = 0; c < 8; c++) {
        bf16x8 kf = *reinterpret_cast<const bf16x8*>(kb + (((lhi << 4) + (c << 6)) ^ sw));
        sacc[kt * 4 + nf] = MFMA16(qf[c], kf, sacc[kt * 4 + nf]);
      }
    }
    WAITL0; BARRIER;
  }
  float madd[16];
#pragma unroll
  for (int f = 0; f < 16; f++) madd[f] = maskf[(f << 4) + llo];
  float mx[4] = {-3e38f, -3e38f, -3e38f, -3e38f};
#pragma unroll
  for (int f = 0; f < 16; f++)
#pragma unroll
    for (int r = 0; r < 4; r++) {
      float sv = sacc[f][r] * 0.0625f + madd[f];
      sacc[f][r] = sv;
      mx[r] = fmaxf(mx[r], sv);
    }
#pragma unroll
  for (int r = 0; r < 4; r++)
#pragma unroll
    for (int d = 1; d < 16; d <<= 1) mx[r] = fmaxf(mx[r], __shfl_xor(mx[r], d));
  float sum[4] = {0.f, 0.f, 0.f, 0.f};
#pragma unroll
  for (int f = 0; f < 16; f++)
#pragma unroll
    for (int r = 0; r < 4; r++) {
      float p = __expf(sacc[f][r] - mx[r]);
      sacc[f][r] = p;
      sum[r] += p;
    }
#pragma unroll
  for (int r = 0; r < 4; r++)
#pragma unroll
    for (int d = 1; d < 16; d <<= 1) sum[r] += __shfl_xor(sum[r], d);
  float rin[4];
#pragma unroll
  for (int r = 0; r < 4; r++) rin[r] = 1.f / sum[r];
#pragma unroll
  for (int r = 0; r < 4; r++) {
    int q = (wid << 4) + (lhi << 2) + r;
    char* pb = (char*)P + (q << 9);
    int sw = (q & 7) << 4;
#pragma unroll
    for (int f = 0; f < 16; f++) {
      int key = (f << 4) + llo;
      *reinterpret_cast<u16*>(pb + ((key << 1) ^ sw)) = f2bf(sacc[f][r] * rin[r]);
    }
  }
  WAITL0;
  f32x4 cacc[16] = {};
#pragma unroll 1
  for (int j = 0; j < 4; j++) {
    if (j < 3) { STAGE_V(j + 1, (j + 1) & 1); WAITV(4); } else { WAITV(0); }
    BARRIER;
    const char* vb0 = kv0 + (j & 1) * 32768;
    bf16x8 pf[2];
    {
      int q = (wid << 4) + llo;
      const char* pb = (const char*)P + (q << 9);
      int sw = (q & 7) << 4;
#pragma unroll
      for (int c = 0; c < 2; c++)
        pf[c] = *reinterpret_cast<const bf16x8*>(pb + (((j << 7) + (c << 6) + (lhi << 4)) ^ sw));
    }
#pragma unroll
    for (int mf = 0; mf < 16; mf++) {
      int dl = (mf << 4) + llo;
      const char* vb = vb0 + (dl << 7);
      int sw = (dl & 7) << 4;
#pragma unroll
      for (int c = 0; c < 2; c++) {
        bf16x8 vf = *reinterpret_cast<const bf16x8*>(vb + (((lhi << 4) + (c << 6)) ^ sw));
        cacc[mf] = MFMA16(vf, pf[c], cacc[mf]);
      }
    }
    if (j < 3) { WAITL0; BARRIER; }
  }
#undef STAGE_K
#undef STAGE_V
  int token = (b << 8) + (half << 7) + (wid << 4) + llo;
  u16* crow = ctx + (size_t)token * 4096 + (h << 8);
#pragma unroll
  for (int mf = 0; mf < 16; mf++) {
    ushort4 u;
    u.x = f2bf(cacc[mf][0]); u.y = f2bf(cacc[mf][1]);
    u.z = f2bf(cacc[mf][2]); u.w = f2bf(cacc[mf][3]);
    *reinterpret_cast<ushort4*>(crow + (mf << 4) + (lhi << 2)) = u;
  }
}

extern "C" void kernel_launch(void* const* d_in, const int* in_sizes, int n_in,
                              void* d_out, int out_size, void* d_ws, size_t ws_size,
                              hipStream_t stream) {
  const float* inp  = (const float*)d_in[0];
  const int*   mask = (const int*)d_in[1];
  const float* w    = (const float*)d_in[2];
  const float* bia  = (const float*)d_in[3];
  const float* qkvw = (const float*)d_in[4];
  const float* ow   = (const float*)d_in[5];
  const size_t MB = 1024ull * 1024ull;
  if (ws_size < 384 * MB) return;  // layout below needs 384 MiB
  char* ws = (char*)d_ws;
  u16* xn   = (u16*)(ws);             // 64 MiB  [0,64)
  u16* qkvT = (u16*)(ws + 64 * MB);   // 96 MiB  [64,160)
  u16* qk   = (u16*)(ws + 160 * MB);  // 128 MiB [160,288): [8192 tok][8192]
  u16* vT   = (u16*)(ws + 288 * MB);  // 64 MiB  [288,352): [b][h][d][s]
  u16* oT2  = (u16*)(ws + 352 * MB);  // 32 MiB  [352,384)
  u16* ctx  = (u16*)(ws);             // overlays xn (dead after QKV GEMM)
  float* out = (float*)d_out;

  prep_fused<<<24576, 256, 0, stream>>>(qkvw, qkvT, ow, oT2, inp, w, bia, xn);
  gemm256<1><<<1536, 512, 0, stream>>>(xn, qkvT, (void*)qk, vT, 8192, 12288, 4096, 48);
  attn_kernel<<<1024, 512, 0, stream>>>(qk, vT, mask, ctx);
  gemm256<2><<<512, 512, 0, stream>>>(ctx, oT2, (void*)out, nullptr, 8192, 4096, 4096, 16);
}